// Round 10
// baseline (204.225 us; speedup 1.0000x reference)
//
#include <hip/hip_runtime.h>
#include <hip/hip_fp16.h>

// N=524288 points, T=32 textures, C=7 channels, R=512.
// out[n,c] = sum_corner w_corner(n) * sum_t mw[n,t] * tex[t,c,y_k,x_k]
//
// v7: v6 with the in-graph hipMemsetAsync replaced by a tiny zero_cursor
// kernel (the 16KB fillBufferAligned node showed 136-139 us in replay).
//   1) zero_cursor + scatter: bucket-sort points into 4096 8x8-texel tiles.
//   2) transpose: (T,C,R,R) f32 -> (C,R,R,T) fp16, vectorized.
//   3) mix_tile: one block per tile; halo'd 36.3 KB LDS tile; channel-per-
//      lane fdot2 dots; rec/mw software pipeline.

#define RR 512
#define TT 32
#define CC 7
#define CAP 256                  // slots per bucket (mean 128, +11 sigma)
#define NBK 4096                 // 64 x-tiles * 64 y-tiles (8x8 texels)
#define CHUNKS_PER_C 324         // 9*9 positions * 4 uint4
#define CSTRIDE 325              // padded channel stride in uint4

typedef float fx2 __attribute__((ext_vector_type(2)));
typedef float fx4 __attribute__((ext_vector_type(4)));
typedef _Float16 h2 __attribute__((ext_vector_type(2)));

// ---------------- zero the bucket cursors (replaces hipMemsetAsync) ----------------
__global__ __launch_bounds__(256) void zero_cursor(int* __restrict__ cursor) {
    cursor[blockIdx.x * 256 + threadIdx.x] = 0;
}

// ---------------- transpose+convert: (T,C,R,R) f32 -> (C,R,R,T) fp16 ----------------
// block: fixed (c, y), 64-wide x slab, all 32 t. 28672 blocks.
__global__ __launch_bounds__(256) void transpose_tex(const float* __restrict__ src,
                                                     uint4* __restrict__ dst) {
    __shared__ float tile[32 * 68];   // [t][x] pad 68 (16B-aligned rows)
    int b  = blockIdx.x;
    int xb = (b & 7) << 6;            // x slab base
    int y  = (b >> 3) & 511;
    int c  = b >> 12;                 // 0..6
    int tid = threadIdx.x;

    // load 32t x 64x floats as float4 (2 per thread)
    const fx4* s4 = (const fx4*)src;
#pragma unroll
    for (int p = 0; p < 2; ++p) {
        int q  = p * 256 + tid;       // 0..511
        int t  = q >> 4;              // 16 float4 per row
        int xv = q & 15;
        fx4 v = s4[(size_t)(((t * 7 + c) * 512 + y) * 512 + xb) / 4 + xv];
        *(fx4*)&tile[t * 68 + 4 * xv] = v;
    }
    __syncthreads();

    // write 4KB contiguous: uint4 o=tid covers x = o>>2, t = (o&3)*8 .. +7
    int x  = tid >> 2;
    int t8 = tid & 3;
    union { uint4 u; __half2 h[4]; } U;
#pragma unroll
    for (int j2 = 0; j2 < 4; ++j2) {
        float lo = tile[(t8 * 8 + 2 * j2) * 68 + x];
        float hi = tile[(t8 * 8 + 2 * j2 + 1) * 68 + x];
        U.h[j2] = __floats2half2_rn(lo, hi);
    }
    dst[(size_t)((c * 512 + y) * 512 + xb + x) * 4 + t8] = U.u;
}

// ---------------- scatter: bucket-sort points into 4096 tiles ----------------
__global__ __launch_bounds__(256) void scatter_pts(const fx2* __restrict__ tc2,
                                                   fx4* __restrict__ recs,
                                                   int* __restrict__ cursor, int N) {
    __shared__ int h[NBK];
    __shared__ int base[NBK];
    int tid = threadIdx.x;
    for (int q = tid; q < NBK; q += 256) h[q] = 0;
    __syncthreads();
    int n = blockIdx.x * 256 + tid;
    int b = 0, rank = 0;
    fx2 xy;
    if (n < N) {
        xy = tc2[n];
        float ix = ((xy.x + 1.0f) * 512.0f - 1.0f) * 0.5f;
        float iy = ((xy.y + 1.0f) * 512.0f - 1.0f) * 0.5f;
        int xi0 = (int)fminf(fmaxf(floorf(ix), 0.0f), 511.0f);
        int yi0 = (int)fminf(fmaxf(floorf(iy), 0.0f), 511.0f);
        b = ((yi0 >> 3) << 6) | (xi0 >> 3);
        rank = atomicAdd(&h[b], 1);
    }
    __syncthreads();
    for (int q = tid; q < NBK; q += 256)
        if (h[q] > 0) base[q] = atomicAdd(&cursor[q], h[q]);
    __syncthreads();
    if (n < N) {
        int slot = base[b] + rank;
        if (slot < CAP) {
            fx4 rec = {xy.x, xy.y, __int_as_float(n), 0.0f};
            recs[(size_t)b * CAP + slot] = rec;
        }
    }
}

// 16-h2 dot of one staged position against the point's mix weights
__device__ __forceinline__ float dot_pos(const uint4* __restrict__ T, int idx,
                                         const h2* __restrict__ mh) {
    float d = 0.0f;
#pragma unroll
    for (int q = 0; q < 4; ++q) {
        union { uint4 u; h2 h[4]; } U;
        U.u = T[idx + q];
#pragma unroll
        for (int j = 0; j < 4; ++j) {
#if __has_builtin(__builtin_amdgcn_fdot2)
            d = __builtin_amdgcn_fdot2(U.h[j], mh[q * 4 + j], d, false);
#else
            d += (float)U.h[j].x * (float)mh[q * 4 + j].x
               + (float)U.h[j].y * (float)mh[q * 4 + j].y;
#endif
        }
    }
    return d;
}

// ---------------- main: one block per tile, LDS-staged texture ----------------
__global__ __launch_bounds__(256) void mix_tile(const fx4* __restrict__ recs,
                                                const int* __restrict__ cnts,
                                                const fx4* __restrict__ mw4,
                                                const uint4* __restrict__ t16,
                                                float* __restrict__ out) {
    __shared__ uint4 TILE[7 * CSTRIDE];          // 36,400 B
    int k  = blockIdx.x;
    int tx = k & 63, ty = k >> 6;
    int X0 = tx << 3, Y0 = ty << 3;
    int tid = threadIdx.x;

    // stage halo'd tile: 7ch x 9 rows x 9 xpos x 64B
    for (int q = tid; q < 7 * CHUNKS_PER_C; q += 256) {
        int c  = q / CHUNKS_PER_C;
        int r  = q - c * CHUNKS_PER_C;
        int yy = r / 36;
        int rr = r - yy * 36;
        int gx = X0 + (rr >> 2); if (gx > 511) gx = 511;
        int gy = Y0 + yy;        if (gy > 511) gy = 511;
        TILE[q + c] = t16[(size_t)((((c << 9) + gy) << 9) | gx) * 4 + (rr & 3)];
    }
    __syncthreads();

    int cnt = cnts[k]; if (cnt > CAP) cnt = CAP;
    int sub = tid & 7;
    int c   = (sub == 7) ? 0 : sub;              // lane 7 duplicates c=0 (no store)
    int cbase = c * CSTRIDE;
    size_t rbase = (size_t)k * CAP;

    int s = tid >> 3;
    if (s >= cnt) return;

    fx4 rec = recs[rbase + s];
    int n = __float_as_int(rec.z);
    fx4 m[8];
#pragma unroll
    for (int j = 0; j < 8; ++j) m[j] = mw4[(size_t)n * 8 + j];

    while (true) {
        int s2 = s + 32;
        bool live2 = s2 < cnt;
        fx4 rec2 = rec;
        if (live2) rec2 = recs[rbase + s2];      // prefetch next rec

        // ---- process current point ----
        float ix = ((rec.x + 1.0f) * 512.0f - 1.0f) * 0.5f;
        float iy = ((rec.y + 1.0f) * 512.0f - 1.0f) * 0.5f;
        float x0f = floorf(ix), y0f = floorf(iy);
        float fxw = ix - x0f, fyw = iy - y0f;
        float gxw = 1.0f - fxw, gyw = 1.0f - fyw;
        float w00 = gxw * gyw, w10 = fxw * gyw, w01 = gxw * fyw, w11 = fxw * fyw;
        bool vx0 = (x0f >= 0.0f), vx1 = (x0f <= 510.0f);
        bool vy0 = (y0f >= 0.0f), vy1 = (y0f <= 510.0f);
        if (!(vx0 && vy0)) w00 = 0.0f;
        if (!(vx1 && vy0)) w10 = 0.0f;
        if (!(vx0 && vy1)) w01 = 0.0f;
        if (!(vx1 && vy1)) w11 = 0.0f;
        int xi0 = (int)fminf(fmaxf(x0f, 0.0f), 511.0f);
        int xi1 = (int)fminf(fmaxf(x0f + 1.0f, 0.0f), 511.0f);
        int yi0 = (int)fminf(fmaxf(y0f, 0.0f), 511.0f);
        int yi1 = (int)fminf(fmaxf(y0f + 1.0f, 0.0f), 511.0f);
        int xl0 = xi0 - X0, xl1 = xi1 - X0;
        int yl0 = yi0 - Y0, yl1 = yi1 - Y0;

        // fp16 mix weights for this point
        h2 mh[16];
#pragma unroll
        for (int j = 0; j < 8; ++j) {
            mh[2 * j]     = h2{(_Float16)m[j].x, (_Float16)m[j].y};
            mh[2 * j + 1] = h2{(_Float16)m[j].z, (_Float16)m[j].w};
        }

        int p00 = cbase + ((yl0 * 9 + xl0) << 2);
        int p10 = cbase + ((yl0 * 9 + xl1) << 2);
        int p01 = cbase + ((yl1 * 9 + xl0) << 2);
        int p11 = cbase + ((yl1 * 9 + xl1) << 2);
        float d = w00 * dot_pos(TILE, p00, mh)
                + w10 * dot_pos(TILE, p10, mh)
                + w01 * dot_pos(TILE, p01, mh)
                + w11 * dot_pos(TILE, p11, mh);

        int nst = n;

        // prefetch next mw (depends on rec2, overlaps with store/loop)
        int n2 = 0;
        if (live2) {
            n2 = __float_as_int(rec2.z);
#pragma unroll
            for (int j = 0; j < 8; ++j) m[j] = mw4[(size_t)n2 * 8 + j];
        }

        if (sub < 7) __builtin_nontemporal_store(d, &out[(size_t)nst * 7 + c]);

        if (!live2) break;
        rec = rec2; n = n2; s = s2;
    }
}

// ---------------- fallback (ws too small): naive, original layout ----------------
__global__ __launch_bounds__(256) void mix_naive(const float* __restrict__ tc,
                                                 const float* __restrict__ mw,
                                                 const float* __restrict__ tex,
                                                 float* __restrict__ out, int N) {
    int n = blockIdx.x * 256 + threadIdx.x;
    if (n >= N) return;
    float x = tc[2 * n], y = tc[2 * n + 1];
    float ix = ((x + 1.0f) * 512.0f - 1.0f) * 0.5f;
    float iy = ((y + 1.0f) * 512.0f - 1.0f) * 0.5f;
    float x0f = floorf(ix), y0f = floorf(iy);
    float fx = ix - x0f, fy = iy - y0f;
    float gx = 1.0f - fx, gy = 1.0f - fy;
    float wgt[4] = {gx * gy, fx * gy, gx * fy, fx * fy};
    bool vx0 = (x0f >= 0.0f), vx1 = (x0f <= 510.0f);
    bool vy0 = (y0f >= 0.0f), vy1 = (y0f <= 510.0f);
    if (!(vx0 && vy0)) wgt[0] = 0.0f;
    if (!(vx1 && vy0)) wgt[1] = 0.0f;
    if (!(vx0 && vy1)) wgt[2] = 0.0f;
    if (!(vx1 && vy1)) wgt[3] = 0.0f;
    int xi0 = (int)fminf(fmaxf(x0f, 0.0f), 511.0f);
    int xi1 = (int)fminf(fmaxf(x0f + 1.0f, 0.0f), 511.0f);
    int yi0 = (int)fminf(fmaxf(y0f, 0.0f), 511.0f);
    int yi1 = (int)fminf(fmaxf(y0f + 1.0f, 0.0f), 511.0f);
    int xs[4] = {xi0, xi1, xi0, xi1};
    int ys[4] = {yi0, yi0, yi1, yi1};

    float acc[7] = {0.f, 0.f, 0.f, 0.f, 0.f, 0.f, 0.f};
#pragma unroll
    for (int kk = 0; kk < 4; ++kk) {
        float wk = wgt[kk];
        int base = ys[kk] * 512 + xs[kk];
        for (int t = 0; t < 32; ++t) {
            float m = wk * mw[(size_t)n * 32 + t];
#pragma unroll
            for (int cc = 0; cc < 7; ++cc)
                acc[cc] = fmaf(m, tex[(t * 7 + cc) * 262144 + base], acc[cc]);
        }
    }
#pragma unroll
    for (int cc = 0; cc < 7; ++cc) out[(size_t)n * 7 + cc] = acc[cc];
}

extern "C" void kernel_launch(void* const* d_in, const int* in_sizes, int n_in,
                              void* d_out, int out_size, void* d_ws, size_t ws_size,
                              hipStream_t stream) {
    const float* tc  = (const float*)d_in[0];
    const float* mw  = (const float*)d_in[1];
    const float* tex = (const float*)d_in[2];
    float* out = (float*)d_out;
    int N = in_sizes[0] / 2;

    const size_t TEXB = (size_t)CC * RR * RR * TT * sizeof(__half);   // 117,440,512
    const size_t RECB = (size_t)NBK * CAP * sizeof(fx4);              //  16,777,216
    const size_t need = TEXB + RECB + NBK * sizeof(int);

    if (ws_size >= need) {
        char* ws = (char*)d_ws;
        uint4* wst  = (uint4*)ws;
        fx4*   recs = (fx4*)(ws + TEXB);
        int*   cur  = (int*)(ws + TEXB + RECB);

        zero_cursor<<<NBK / 256, 256, 0, stream>>>(cur);
        scatter_pts<<<(N + 255) / 256, 256, 0, stream>>>((const fx2*)tc, recs, cur, N);
        transpose_tex<<<7 * 512 * 8, 256, 0, stream>>>(tex, wst);
        mix_tile<<<NBK, 256, 0, stream>>>((const fx4*)recs, (const int*)cur,
                                          (const fx4*)mw, (const uint4*)wst, out);
    } else {
        mix_naive<<<(N + 255) / 256, 256, 0, stream>>>(tc, mw, tex, out, N);
    }
}

// Round 11
// 176.646 us; speedup vs baseline: 1.1561x; 1.1561x over previous
//
#include <hip/hip_runtime.h>
#include <hip/hip_fp16.h>

// N=524288 points, T=32 textures, C=7 channels, R=512.
// out[n,c] = sum_corner w_corner(n) * sum_t mw[n,t] * tex[t,c,y_k,x_k]
//
// v8: v7 with the scatter rebuilt around the atomic-serialization theory:
//   - cursors strided 1-per-64B-line (cursor[b*16]) -> per-line atomic chain
//     drops ~16x (device-scope atomics appear to serialize per line).
//   - direct per-point atomicAdd (the LDS histogram aggregated nothing at
//     256 pts / 4096 buckets and its scans were pure overhead).
// transpose_tex / mix_tile unchanged from the passing v7.

#define RR 512
#define TT 32
#define CC 7
#define CAP 256                  // slots per bucket (mean 128, max ~174)
#define NBK 4096                 // 64 x-tiles * 64 y-tiles (8x8 texels)
#define CHUNKS_PER_C 324         // 9*9 positions * 4 uint4
#define CSTRIDE 325              // padded channel stride in uint4

typedef float fx2 __attribute__((ext_vector_type(2)));
typedef float fx4 __attribute__((ext_vector_type(4)));
typedef _Float16 h2 __attribute__((ext_vector_type(2)));

// ---------------- zero the strided bucket cursors ----------------
__global__ __launch_bounds__(256) void zero_cursor(int* __restrict__ cursor) {
    cursor[blockIdx.x * 256 + threadIdx.x] = 0;   // grid 256 -> 65536 ints
}

// ---------------- transpose+convert: (T,C,R,R) f32 -> (C,R,R,T) fp16 ----------------
// block: fixed (c, y), 64-wide x slab, all 32 t. 28672 blocks.
__global__ __launch_bounds__(256) void transpose_tex(const float* __restrict__ src,
                                                     uint4* __restrict__ dst) {
    __shared__ float tile[32 * 68];   // [t][x] pad 68 (16B-aligned rows)
    int b  = blockIdx.x;
    int xb = (b & 7) << 6;            // x slab base
    int y  = (b >> 3) & 511;
    int c  = b >> 12;                 // 0..6
    int tid = threadIdx.x;

    const fx4* s4 = (const fx4*)src;
#pragma unroll
    for (int p = 0; p < 2; ++p) {
        int q  = p * 256 + tid;       // 0..511
        int t  = q >> 4;              // 16 float4 per row
        int xv = q & 15;
        fx4 v = s4[(size_t)(((t * 7 + c) * 512 + y) * 512 + xb) / 4 + xv];
        *(fx4*)&tile[t * 68 + 4 * xv] = v;
    }
    __syncthreads();

    int x  = tid >> 2;
    int t8 = tid & 3;
    union { uint4 u; __half2 h[4]; } U;
#pragma unroll
    for (int j2 = 0; j2 < 4; ++j2) {
        float lo = tile[(t8 * 8 + 2 * j2) * 68 + x];
        float hi = tile[(t8 * 8 + 2 * j2 + 1) * 68 + x];
        U.h[j2] = __floats2half2_rn(lo, hi);
    }
    dst[(size_t)((c * 512 + y) * 512 + xb + x) * 4 + t8] = U.u;
}

// ---------------- scatter: direct per-point atomic, strided cursors ----------------
__global__ __launch_bounds__(256) void scatter_direct(const fx2* __restrict__ tc2,
                                                      fx4* __restrict__ recs,
                                                      int* __restrict__ cursor, int N) {
    int n = blockIdx.x * 256 + threadIdx.x;
    if (n >= N) return;
    fx2 xy = tc2[n];
    float ix = ((xy.x + 1.0f) * 512.0f - 1.0f) * 0.5f;
    float iy = ((xy.y + 1.0f) * 512.0f - 1.0f) * 0.5f;
    int xi0 = (int)fminf(fmaxf(floorf(ix), 0.0f), 511.0f);
    int yi0 = (int)fminf(fmaxf(floorf(iy), 0.0f), 511.0f);
    int b = ((yi0 >> 3) << 6) | (xi0 >> 3);
    int slot = atomicAdd(&cursor[b << 4], 1);     // 1 cursor per 64B line
    if (slot < CAP) {
        fx4 rec = {xy.x, xy.y, __int_as_float(n), 0.0f};
        recs[(size_t)b * CAP + slot] = rec;
    }
}

// 16-h2 dot of one staged position against the point's mix weights
__device__ __forceinline__ float dot_pos(const uint4* __restrict__ T, int idx,
                                         const h2* __restrict__ mh) {
    float d = 0.0f;
#pragma unroll
    for (int q = 0; q < 4; ++q) {
        union { uint4 u; h2 h[4]; } U;
        U.u = T[idx + q];
#pragma unroll
        for (int j = 0; j < 4; ++j) {
#if __has_builtin(__builtin_amdgcn_fdot2)
            d = __builtin_amdgcn_fdot2(U.h[j], mh[q * 4 + j], d, false);
#else
            d += (float)U.h[j].x * (float)mh[q * 4 + j].x
               + (float)U.h[j].y * (float)mh[q * 4 + j].y;
#endif
        }
    }
    return d;
}

// ---------------- main: one block per tile, LDS-staged texture ----------------
__global__ __launch_bounds__(256) void mix_tile(const fx4* __restrict__ recs,
                                                const int* __restrict__ cnts,
                                                const fx4* __restrict__ mw4,
                                                const uint4* __restrict__ t16,
                                                float* __restrict__ out) {
    __shared__ uint4 TILE[7 * CSTRIDE];          // 36,400 B
    int k  = blockIdx.x;
    int tx = k & 63, ty = k >> 6;
    int X0 = tx << 3, Y0 = ty << 3;
    int tid = threadIdx.x;

    // stage halo'd tile: 7ch x 9 rows x 9 xpos x 64B
    for (int q = tid; q < 7 * CHUNKS_PER_C; q += 256) {
        int c  = q / CHUNKS_PER_C;
        int r  = q - c * CHUNKS_PER_C;
        int yy = r / 36;
        int rr = r - yy * 36;
        int gx = X0 + (rr >> 2); if (gx > 511) gx = 511;
        int gy = Y0 + yy;        if (gy > 511) gy = 511;
        TILE[q + c] = t16[(size_t)((((c << 9) + gy) << 9) | gx) * 4 + (rr & 3)];
    }
    __syncthreads();

    int cnt = cnts[k << 4]; if (cnt > CAP) cnt = CAP;
    int sub = tid & 7;
    int c   = (sub == 7) ? 0 : sub;              // lane 7 duplicates c=0 (no store)
    int cbase = c * CSTRIDE;
    size_t rbase = (size_t)k * CAP;

    int s = tid >> 3;
    if (s >= cnt) return;

    fx4 rec = recs[rbase + s];
    int n = __float_as_int(rec.z);
    fx4 m[8];
#pragma unroll
    for (int j = 0; j < 8; ++j) m[j] = mw4[(size_t)n * 8 + j];

    while (true) {
        int s2 = s + 32;
        bool live2 = s2 < cnt;
        fx4 rec2 = rec;
        if (live2) rec2 = recs[rbase + s2];      // prefetch next rec

        // ---- process current point ----
        float ix = ((rec.x + 1.0f) * 512.0f - 1.0f) * 0.5f;
        float iy = ((rec.y + 1.0f) * 512.0f - 1.0f) * 0.5f;
        float x0f = floorf(ix), y0f = floorf(iy);
        float fxw = ix - x0f, fyw = iy - y0f;
        float gxw = 1.0f - fxw, gyw = 1.0f - fyw;
        float w00 = gxw * gyw, w10 = fxw * gyw, w01 = gxw * fyw, w11 = fxw * fyw;
        bool vx0 = (x0f >= 0.0f), vx1 = (x0f <= 510.0f);
        bool vy0 = (y0f >= 0.0f), vy1 = (y0f <= 510.0f);
        if (!(vx0 && vy0)) w00 = 0.0f;
        if (!(vx1 && vy0)) w10 = 0.0f;
        if (!(vx0 && vy1)) w01 = 0.0f;
        if (!(vx1 && vy1)) w11 = 0.0f;
        int xi0 = (int)fminf(fmaxf(x0f, 0.0f), 511.0f);
        int xi1 = (int)fminf(fmaxf(x0f + 1.0f, 0.0f), 511.0f);
        int yi0 = (int)fminf(fmaxf(y0f, 0.0f), 511.0f);
        int yi1 = (int)fminf(fmaxf(y0f + 1.0f, 0.0f), 511.0f);
        int xl0 = xi0 - X0, xl1 = xi1 - X0;
        int yl0 = yi0 - Y0, yl1 = yi1 - Y0;

        // fp16 mix weights for this point
        h2 mh[16];
#pragma unroll
        for (int j = 0; j < 8; ++j) {
            mh[2 * j]     = h2{(_Float16)m[j].x, (_Float16)m[j].y};
            mh[2 * j + 1] = h2{(_Float16)m[j].z, (_Float16)m[j].w};
        }

        int p00 = cbase + ((yl0 * 9 + xl0) << 2);
        int p10 = cbase + ((yl0 * 9 + xl1) << 2);
        int p01 = cbase + ((yl1 * 9 + xl0) << 2);
        int p11 = cbase + ((yl1 * 9 + xl1) << 2);
        float d = w00 * dot_pos(TILE, p00, mh)
                + w10 * dot_pos(TILE, p10, mh)
                + w01 * dot_pos(TILE, p01, mh)
                + w11 * dot_pos(TILE, p11, mh);

        int nst = n;

        // prefetch next mw (depends on rec2, overlaps with store/loop)
        int n2 = 0;
        if (live2) {
            n2 = __float_as_int(rec2.z);
#pragma unroll
            for (int j = 0; j < 8; ++j) m[j] = mw4[(size_t)n2 * 8 + j];
        }

        if (sub < 7) __builtin_nontemporal_store(d, &out[(size_t)nst * 7 + c]);

        if (!live2) break;
        rec = rec2; n = n2; s = s2;
    }
}

// ---------------- fallback (ws too small): naive, original layout ----------------
__global__ __launch_bounds__(256) void mix_naive(const float* __restrict__ tc,
                                                 const float* __restrict__ mw,
                                                 const float* __restrict__ tex,
                                                 float* __restrict__ out, int N) {
    int n = blockIdx.x * 256 + threadIdx.x;
    if (n >= N) return;
    float x = tc[2 * n], y = tc[2 * n + 1];
    float ix = ((x + 1.0f) * 512.0f - 1.0f) * 0.5f;
    float iy = ((y + 1.0f) * 512.0f - 1.0f) * 0.5f;
    float x0f = floorf(ix), y0f = floorf(iy);
    float fx = ix - x0f, fy = iy - y0f;
    float gx = 1.0f - fx, gy = 1.0f - fy;
    float wgt[4] = {gx * gy, fx * gy, gx * fy, fx * fy};
    bool vx0 = (x0f >= 0.0f), vx1 = (x0f <= 510.0f);
    bool vy0 = (y0f >= 0.0f), vy1 = (y0f <= 510.0f);
    if (!(vx0 && vy0)) wgt[0] = 0.0f;
    if (!(vx1 && vy0)) wgt[1] = 0.0f;
    if (!(vx0 && vy1)) wgt[2] = 0.0f;
    if (!(vx1 && vy1)) wgt[3] = 0.0f;
    int xi0 = (int)fminf(fmaxf(x0f, 0.0f), 511.0f);
    int xi1 = (int)fminf(fmaxf(x0f + 1.0f, 0.0f), 511.0f);
    int yi0 = (int)fminf(fmaxf(y0f, 0.0f), 511.0f);
    int yi1 = (int)fminf(fmaxf(y0f + 1.0f, 0.0f), 511.0f);
    int xs[4] = {xi0, xi1, xi0, xi1};
    int ys[4] = {yi0, yi0, yi1, yi1};

    float acc[7] = {0.f, 0.f, 0.f, 0.f, 0.f, 0.f, 0.f};
#pragma unroll
    for (int kk = 0; kk < 4; ++kk) {
        float wk = wgt[kk];
        int base = ys[kk] * 512 + xs[kk];
        for (int t = 0; t < 32; ++t) {
            float m = wk * mw[(size_t)n * 32 + t];
#pragma unroll
            for (int cc = 0; cc < 7; ++cc)
                acc[cc] = fmaf(m, tex[(t * 7 + cc) * 262144 + base], acc[cc]);
        }
    }
#pragma unroll
    for (int cc = 0; cc < 7; ++cc) out[(size_t)n * 7 + cc] = acc[cc];
}

extern "C" void kernel_launch(void* const* d_in, const int* in_sizes, int n_in,
                              void* d_out, int out_size, void* d_ws, size_t ws_size,
                              hipStream_t stream) {
    const float* tc  = (const float*)d_in[0];
    const float* mw  = (const float*)d_in[1];
    const float* tex = (const float*)d_in[2];
    float* out = (float*)d_out;
    int N = in_sizes[0] / 2;

    const size_t TEXB = (size_t)CC * RR * RR * TT * sizeof(__half);   // 117,440,512
    const size_t RECB = (size_t)NBK * CAP * sizeof(fx4);              //  16,777,216
    const size_t CURB = (size_t)NBK * 16 * sizeof(int);               //     262,144
    const size_t need = TEXB + RECB + CURB;

    if (ws_size >= need) {
        char* ws = (char*)d_ws;
        uint4* wst  = (uint4*)ws;
        fx4*   recs = (fx4*)(ws + TEXB);
        int*   cur  = (int*)(ws + TEXB + RECB);

        zero_cursor<<<NBK * 16 / 256, 256, 0, stream>>>(cur);
        scatter_direct<<<(N + 255) / 256, 256, 0, stream>>>((const fx2*)tc, recs, cur, N);
        transpose_tex<<<7 * 512 * 8, 256, 0, stream>>>(tex, wst);
        mix_tile<<<NBK, 256, 0, stream>>>((const fx4*)recs, (const int*)cur,
                                          (const fx4*)mw, (const uint4*)wst, out);
    } else {
        mix_naive<<<(N + 255) / 256, 256, 0, stream>>>(tc, mw, tex, out, N);
    }
}